// Round 2
// baseline (2442.039 us; speedup 1.0000x reference)
//
#include <hip/hip_runtime.h>
#include <math.h>

#define NSEQ 2048
#define CDIM 768
#define NH   12
#define HD   64
#define NB   2

typedef unsigned short u16;
typedef __attribute__((ext_vector_type(8))) short bf16x8;   // 8 bf16 = 4 VGPRs
typedef __attribute__((ext_vector_type(4))) float f32x4;
typedef __attribute__((ext_vector_type(8))) unsigned short ushort8;

// fp32 -> bf16 round-to-nearest-even (no NaN inputs here)
__device__ __forceinline__ u16 f2bf(float x) {
    unsigned int u = __float_as_uint(x);
    u += 0x7fffu + ((u >> 16) & 1u);
    return (u16)(u >> 16);
}

// ---------------------------------------------------------------------------
// Kernel 1: qkv = X @ Wqkv^T (fp32 GEMM); fused scale (q), RoPE (q,k),
// head transpose, bf16 convert. Q,K: [B,H,N,64] bf16. V: [B,H,64,N] bf16
// (transposed so attention's V B-fragments are contiguous ds_read_b128).
// ---------------------------------------------------------------------------
__global__ __launch_bounds__(256)
void qkv_rope_kernel(const float* __restrict__ X, const float* __restrict__ W,
                     u16* __restrict__ Qb, u16* __restrict__ Kb,
                     u16* __restrict__ Vb)
{
    __shared__ float As[128 * 32];
    __shared__ float Bs[128 * 32];
    const int tid = threadIdx.x;
    const int tx = tid & 15, ty = tid >> 4;
    const int m0 = blockIdx.x * 128;
    const int n0 = blockIdx.y * 128;

    float acc[8][8];
#pragma unroll
    for (int i = 0; i < 8; ++i)
#pragma unroll
        for (int j = 0; j < 8; ++j) acc[i][j] = 0.f;

    for (int kt = 0; kt < CDIM; kt += 32) {
        __syncthreads();
#pragma unroll
        for (int it = 0; it < 4; ++it) {
            int idx = tid + 256 * it;
            int row = idx >> 3;
            int c4  = (idx & 7) << 2;
            *(float4*)&As[row * 32 + c4] =
                *(const float4*)&X[(size_t)(m0 + row) * CDIM + kt + c4];
            *(float4*)&Bs[row * 32 + c4] =
                *(const float4*)&W[(size_t)(n0 + row) * CDIM + kt + c4];
        }
        __syncthreads();
        const float4* As4 = (const float4*)As;
        const float4* Bs4 = (const float4*)Bs;
#pragma unroll
        for (int kq = 0; kq < 8; ++kq) {
            const int ke = (kq + tx) & 7;
            float4 a[8], b[8];
#pragma unroll
            for (int i = 0; i < 8; ++i) a[i] = As4[(ty * 8 + i) * 8 + ke];
#pragma unroll
            for (int j = 0; j < 8; ++j) b[j] = Bs4[(tx * 8 + j) * 8 + ke];
#pragma unroll
            for (int i = 0; i < 8; ++i)
#pragma unroll
                for (int j = 0; j < 8; ++j) {
                    acc[i][j] = fmaf(a[i].x, b[j].x, acc[i][j]);
                    acc[i][j] = fmaf(a[i].y, b[j].y, acc[i][j]);
                    acc[i][j] = fmaf(a[i].z, b[j].z, acc[i][j]);
                    acc[i][j] = fmaf(a[i].w, b[j].w, acc[i][j]);
                }
        }
    }

    // Epilogue. 768 = 6*128 -> q/k/v selector and batch index block-uniform.
    const int nb  = n0 + tx * 8;
    const int sel = nb / CDIM;       // 0=q, 1=k, 2=v
    const int rem = nb % CDIM;
    const int h   = rem >> 6;
    const int dd  = rem & 63;
    const int bi  = m0 >> 11;        // block never straddles the batch edge
    const int nn0 = (m0 & 2047) + ty * 8;

    const float scl = (sel == 0) ? 0.125f : 1.0f;   // d^-0.5, q only

    if (sel == 2) {
        // V transposed: Vb[((bi*NH+h)*64 + d)*2048 + n], 8 consecutive n
#pragma unroll
        for (int j = 0; j < 8; ++j) {
            ushort8 v;
#pragma unroll
            for (int i = 0; i < 8; ++i) v[i] = f2bf(acc[i][j]);
            size_t addr = (((size_t)(bi * NH + h)) * HD + dd + j) * NSEQ + nn0;
            *(ushort8*)&Vb[addr] = v;
        }
    } else {
        u16* dst = (sel == 0) ? Qb : Kb;
        float invf[4];
#pragma unroll
        for (int p = 0; p < 4; ++p)
            invf[p] = expf(-0.14391156831212787f * (float)(dd + 2 * p));
#pragma unroll
        for (int i = 0; i < 8; ++i) {
            int nn = nn0 + i;
            float fn = (float)nn;
            ushort8 o;
#pragma unroll
            for (int p = 0; p < 4; ++p) {
                float ang = fn * invf[p];
                float sv = sinf(ang), cv = cosf(ang);
                float e0 = acc[i][2 * p]     * scl;
                float e1 = acc[i][2 * p + 1] * scl;
                o[2 * p]     = f2bf(e0 * cv - e1 * sv);
                o[2 * p + 1] = f2bf(e1 * cv + e0 * sv);
            }
            size_t base = (((size_t)(bi * NH + h)) * NSEQ + nn) * HD + dd;
            *(ushort8*)&dst[base] = o;
        }
    }
}

// ---------------------------------------------------------------------------
// Kernel 2: flash attention, bf16 MFMA (16x16x32). 4 waves x 16 q-rows per
// WG, 64-key tiles. LDS stride 72 bf16 (+8 pad -> 2-way conflicts, free).
// Fragment layouts (HW-verified): A[m=lane&15][k=quad*8+j];
// B[n=lane&15][k=quad*8+j]; C/D col=lane&15, row=quad*4+reg.
// P round-trips through wave-private LDS (wave-ordered DS, no barrier).
// ---------------------------------------------------------------------------
#define LSTR 72

__global__ __launch_bounds__(256)
void attn_kernel(const u16* __restrict__ Qb, const u16* __restrict__ Kb,
                 const u16* __restrict__ Vt, float* __restrict__ AO)
{
    __shared__ u16 Qs[64 * LSTR];
    __shared__ u16 Ks[64 * LSTR];
    __shared__ u16 Vs[64 * LSTR];   // [d][key]
    __shared__ u16 Ps[64 * LSTR];   // 4 waves x [16 qrows][64 keys]

    const int tid  = threadIdx.x;
    const int lane = tid & 63;
    const int wid  = tid >> 6;
    const int l15  = lane & 15;
    const int quad = lane >> 4;
    const int qt = blockIdx.x;      // 0..31
    const int bh = blockIdx.y;      // 0..23

    const u16* Qg = Qb + ((size_t)bh * NSEQ + qt * 64) * HD;
    const u16* Kg = Kb + (size_t)bh * NSEQ * HD;
    const u16* Vg = Vt + (size_t)bh * HD * NSEQ;   // [64][2048]

    // stage Q (64 rows x 64 bf16)
#pragma unroll
    for (int it = 0; it < 2; ++it) {
        int idx = tid + 256 * it;
        int row = idx >> 3, c8 = (idx & 7) << 3;
        *(uint4*)&Qs[row * LSTR + c8] = *(const uint4*)&Qg[row * HD + c8];
    }
    __syncthreads();

    // A-fragments of Q are loop-invariant: load once
    bf16x8 aq[2];
#pragma unroll
    for (int k = 0; k < 2; ++k)
        aq[k] = *(const bf16x8*)&Qs[(wid * 16 + l15) * LSTR + quad * 8 + 32 * k];

    float m_i[4], l_i[4];
    f32x4 O[4];
#pragma unroll
    for (int r = 0; r < 4; ++r) { m_i[r] = -1e30f; l_i[r] = 0.f; }
#pragma unroll
    for (int t = 0; t < 4; ++t) O[t] = (f32x4){0.f, 0.f, 0.f, 0.f};

    u16* Pw = Ps + wid * 16 * LSTR;

    for (int kt = 0; kt < NSEQ / 64; ++kt) {
        __syncthreads();   // previous iteration's frag reads done
#pragma unroll
        for (int it = 0; it < 2; ++it) {
            int idx = tid + 256 * it;
            int row = idx >> 3, c8 = (idx & 7) << 3;
            *(uint4*)&Ks[row * LSTR + c8] =
                *(const uint4*)&Kg[(size_t)(kt * 64 + row) * HD + c8];
            *(uint4*)&Vs[row * LSTR + c8] =
                *(const uint4*)&Vg[(size_t)row * NSEQ + kt * 64 + c8];
        }
        __syncthreads();

        // S = Q . K^T : 4 col-tiles x 2 k-steps
        f32x4 sacc[4];
#pragma unroll
        for (int c = 0; c < 4; ++c) sacc[c] = (f32x4){0.f, 0.f, 0.f, 0.f};
#pragma unroll
        for (int k = 0; k < 2; ++k) {
#pragma unroll
            for (int c = 0; c < 4; ++c) {
                bf16x8 bk = *(const bf16x8*)
                    &Ks[(c * 16 + l15) * LSTR + quad * 8 + 32 * k];
                sacc[c] = __builtin_amdgcn_mfma_f32_16x16x32_bf16(
                    aq[k], bk, sacc[c], 0, 0, 0);
            }
        }

        // online softmax; lane holds rows quad*4+r, cols 16c+l15
        float alpha[4], p[4][4];
#pragma unroll
        for (int r = 0; r < 4; ++r) {
            float mt = fmaxf(fmaxf(sacc[0][r], sacc[1][r]),
                             fmaxf(sacc[2][r], sacc[3][r]));
            mt = fmaxf(mt, __shfl_xor(mt, 1));
            mt = fmaxf(mt, __shfl_xor(mt, 2));
            mt = fmaxf(mt, __shfl_xor(mt, 4));
            mt = fmaxf(mt, __shfl_xor(mt, 8));
            float mn = fmaxf(m_i[r], mt);
            alpha[r] = __expf(m_i[r] - mn);
            m_i[r] = mn;
            float rs = 0.f;
#pragma unroll
            for (int c = 0; c < 4; ++c) {
                float pv = __expf(sacc[c][r] - mn);
                p[c][r] = pv;
                rs += pv;
            }
            rs += __shfl_xor(rs, 1);
            rs += __shfl_xor(rs, 2);
            rs += __shfl_xor(rs, 4);
            rs += __shfl_xor(rs, 8);
            l_i[r] = l_i[r] * alpha[r] + rs;
        }

        // P -> wave-private LDS (bf16, row-major [16][LSTR])
#pragma unroll
        for (int c = 0; c < 4; ++c)
#pragma unroll
            for (int r = 0; r < 4; ++r)
                Pw[(quad * 4 + r) * LSTR + c * 16 + l15] = f2bf(p[c][r]);

        // rescale O
#pragma unroll
        for (int t = 0; t < 4; ++t)
#pragma unroll
            for (int r = 0; r < 4; ++r) O[t][r] *= alpha[r];

        // O += P . V : A = P rows, B = Vt (d-major)
#pragma unroll
        for (int k = 0; k < 2; ++k) {
            bf16x8 ap = *(const bf16x8*)&Pw[l15 * LSTR + quad * 8 + 32 * k];
#pragma unroll
            for (int t = 0; t < 4; ++t) {
                bf16x8 bv = *(const bf16x8*)
                    &Vs[(t * 16 + l15) * LSTR + quad * 8 + 32 * k];
                O[t] = __builtin_amdgcn_mfma_f32_16x16x32_bf16(
                    ap, bv, O[t], 0, 0, 0);
            }
        }
    }

    // normalize, store fp32 to AO [B*N, C]
    const int b = bh / NH, h = bh % NH;
#pragma unroll
    for (int r = 0; r < 4; ++r) {
        float inv = 1.0f / l_i[r];
        size_t row = (size_t)b * NSEQ + qt * 64 + wid * 16 + quad * 4 + r;
#pragma unroll
        for (int t = 0; t < 4; ++t)
            AO[row * CDIM + h * HD + t * 16 + l15] = O[t][r] * inv;
    }
}

// ---------------------------------------------------------------------------
// Kernel 3: out = AO @ Wproj^T + bias (fp32). Tiles 128x64x32, 8x4 micro.
// ---------------------------------------------------------------------------
__global__ __launch_bounds__(256)
void proj_kernel(const float* __restrict__ A, const float* __restrict__ W,
                 const float* __restrict__ bias, float* __restrict__ out)
{
    __shared__ float As[128 * 32];
    __shared__ float Bs[64 * 32];
    const int tid = threadIdx.x, tx = tid & 15, ty = tid >> 4;
    const int m0 = blockIdx.x * 128;
    const int n0 = blockIdx.y * 64;

    float acc[8][4];
#pragma unroll
    for (int i = 0; i < 8; ++i)
#pragma unroll
        for (int j = 0; j < 4; ++j) acc[i][j] = 0.f;

    for (int kt = 0; kt < CDIM; kt += 32) {
        __syncthreads();
#pragma unroll
        for (int it = 0; it < 4; ++it) {
            int idx = tid + 256 * it;
            int row = idx >> 3, c4 = (idx & 7) << 2;
            *(float4*)&As[row * 32 + c4] =
                *(const float4*)&A[(size_t)(m0 + row) * CDIM + kt + c4];
        }
#pragma unroll
        for (int it = 0; it < 2; ++it) {
            int idx = tid + 256 * it;
            int row = idx >> 3, c4 = (idx & 7) << 2;
            *(float4*)&Bs[row * 32 + c4] =
                *(const float4*)&W[(size_t)(n0 + row) * CDIM + kt + c4];
        }
        __syncthreads();
        const float4* As4 = (const float4*)As;
        const float4* Bs4 = (const float4*)Bs;
#pragma unroll
        for (int kq = 0; kq < 8; ++kq) {
            const int ke = (kq + tx) & 7;
            float4 a[8], b[4];
#pragma unroll
            for (int i = 0; i < 8; ++i) a[i] = As4[(ty * 8 + i) * 8 + ke];
#pragma unroll
            for (int j = 0; j < 4; ++j) b[j] = Bs4[(tx * 4 + j) * 8 + ke];
#pragma unroll
            for (int i = 0; i < 8; ++i)
#pragma unroll
                for (int j = 0; j < 4; ++j) {
                    acc[i][j] = fmaf(a[i].x, b[j].x, acc[i][j]);
                    acc[i][j] = fmaf(a[i].y, b[j].y, acc[i][j]);
                    acc[i][j] = fmaf(a[i].z, b[j].z, acc[i][j]);
                    acc[i][j] = fmaf(a[i].w, b[j].w, acc[i][j]);
                }
        }
    }

    float4 bb = *(const float4*)&bias[n0 + tx * 4];
#pragma unroll
    for (int i = 0; i < 8; ++i) {
        size_t m = (size_t)(m0 + ty * 8 + i);
        *(float4*)&out[m * CDIM + n0 + tx * 4] =
            make_float4(acc[i][0] + bb.x, acc[i][1] + bb.y,
                        acc[i][2] + bb.z, acc[i][3] + bb.w);
    }
}

// ---------------------------------------------------------------------------
extern "C" void kernel_launch(void* const* d_in, const int* in_sizes, int n_in,
                              void* d_out, int out_size, void* d_ws,
                              size_t ws_size, hipStream_t stream)
{
    const float* X     = (const float*)d_in[0];   // [2, 2048, 768]
    const float* Wqkv  = (const float*)d_in[1];   // [2304, 768]
    const float* Wproj = (const float*)d_in[2];   // [768, 768]
    const float* bias  = (const float*)d_in[3];   // [768]
    float* out = (float*)d_out;                   // [2, 2048, 768]

    const size_t per_buf = (size_t)NB * NH * NSEQ * HD;  // 3145728 elems
    u16* Qb = (u16*)d_ws;
    u16* Kb = Qb + per_buf;
    u16* Vb = Kb + per_buf;                       // [B,H,64,N]
    float* AO = (float*)(Vb + per_buf);           // [4096, 768] fp32

    qkv_rope_kernel<<<dim3(32, 18), 256, 0, stream>>>(X, Wqkv, Qb, Kb, Vb);
    attn_kernel<<<dim3(32, 24), 256, 0, stream>>>(Qb, Kb, Vb, AO);
    proj_kernel<<<dim3(32, 12), 256, 0, stream>>>(AO, Wproj, bias, out);
}

// Round 3
// 2362.976 us; speedup vs baseline: 1.0335x; 1.0335x over previous
//
#include <hip/hip_runtime.h>
#include <math.h>

#define NSEQ 2048
#define CDIM 768
#define NH   12
#define HD   64
#define NB   2

typedef unsigned short u16;
typedef __attribute__((ext_vector_type(8))) short bf16x8;   // 8 bf16 = 4 VGPRs
typedef __attribute__((ext_vector_type(4))) float f32x4;
typedef __attribute__((ext_vector_type(8))) unsigned short ushort8;
typedef __attribute__((ext_vector_type(4))) unsigned short ushort4v;

// fp32 -> bf16 round-to-nearest-even (no NaN inputs here)
__device__ __forceinline__ u16 f2bf(float x) {
    unsigned int u = __float_as_uint(x);
    u += 0x7fffu + ((u >> 16) & 1u);
    return (u16)(u >> 16);
}

// ---------------------------------------------------------------------------
// Kernel 0: Wproj fp32 -> bf16 (589824 elements, 4/thread)
// ---------------------------------------------------------------------------
__global__ __launch_bounds__(256)
void wconv_kernel(const float* __restrict__ W, u16* __restrict__ Wb)
{
    int i = (blockIdx.x * 256 + threadIdx.x) * 4;
    float4 v = *(const float4*)&W[i];
    ushort4v o;
    o.x = f2bf(v.x); o.y = f2bf(v.y); o.z = f2bf(v.z); o.w = f2bf(v.w);
    *(ushort4v*)&Wb[i] = o;
}

// ---------------------------------------------------------------------------
// Kernel 1: qkv = X @ Wqkv^T (fp32 GEMM); fused scale (q), RoPE (q,k),
// head transpose, bf16 convert. Q,K: [B,H,N,64] bf16. V: [B,H,64,N] bf16.
// __launch_bounds__(256,1): R2 post-mortem showed the default budget chose
// VGPR=60 and spilled acc[8][8] to scratch (8.4 GB HBM traffic, 2400 us).
// ---------------------------------------------------------------------------
__global__ __launch_bounds__(256, 1)
void qkv_rope_kernel(const float* __restrict__ X, const float* __restrict__ W,
                     u16* __restrict__ Qb, u16* __restrict__ Kb,
                     u16* __restrict__ Vb)
{
    __shared__ float As[128 * 32];
    __shared__ float Bs[128 * 32];
    const int tid = threadIdx.x;
    const int tx = tid & 15, ty = tid >> 4;
    const int m0 = blockIdx.x * 128;
    const int n0 = blockIdx.y * 128;

    float acc[8][8];
#pragma unroll
    for (int i = 0; i < 8; ++i)
#pragma unroll
        for (int j = 0; j < 8; ++j) acc[i][j] = 0.f;

    for (int kt = 0; kt < CDIM; kt += 32) {
        __syncthreads();
#pragma unroll
        for (int it = 0; it < 4; ++it) {
            int idx = tid + 256 * it;
            int row = idx >> 3;
            int c4  = (idx & 7) << 2;
            *(float4*)&As[row * 32 + c4] =
                *(const float4*)&X[(size_t)(m0 + row) * CDIM + kt + c4];
            *(float4*)&Bs[row * 32 + c4] =
                *(const float4*)&W[(size_t)(n0 + row) * CDIM + kt + c4];
        }
        __syncthreads();
        const float4* As4 = (const float4*)As;
        const float4* Bs4 = (const float4*)Bs;
#pragma unroll
        for (int kq = 0; kq < 8; ++kq) {
            const int ke = (kq + tx) & 7;
            float4 a[8], b[8];
#pragma unroll
            for (int i = 0; i < 8; ++i) a[i] = As4[(ty * 8 + i) * 8 + ke];
#pragma unroll
            for (int j = 0; j < 8; ++j) b[j] = Bs4[(tx * 8 + j) * 8 + ke];
#pragma unroll
            for (int i = 0; i < 8; ++i)
#pragma unroll
                for (int j = 0; j < 8; ++j) {
                    acc[i][j] = fmaf(a[i].x, b[j].x, acc[i][j]);
                    acc[i][j] = fmaf(a[i].y, b[j].y, acc[i][j]);
                    acc[i][j] = fmaf(a[i].z, b[j].z, acc[i][j]);
                    acc[i][j] = fmaf(a[i].w, b[j].w, acc[i][j]);
                }
        }
    }

    // Epilogue. 768 = 6*128 -> q/k/v selector and batch index block-uniform.
    const int nb  = n0 + tx * 8;
    const int sel = nb / CDIM;       // 0=q, 1=k, 2=v
    const int rem = nb % CDIM;
    const int h   = rem >> 6;
    const int dd  = rem & 63;
    const int bi  = m0 >> 11;        // block never straddles the batch edge
    const int nn0 = (m0 & 2047) + ty * 8;

    const float scl = (sel == 0) ? 0.125f : 1.0f;   // d^-0.5, q only

    if (sel == 2) {
        // V transposed: Vb[((bi*NH+h)*64 + d)*2048 + n], 8 consecutive n
#pragma unroll
        for (int j = 0; j < 8; ++j) {
            ushort8 v;
#pragma unroll
            for (int i = 0; i < 8; ++i) v[i] = f2bf(acc[i][j]);
            size_t addr = (((size_t)(bi * NH + h)) * HD + dd + j) * NSEQ + nn0;
            *(ushort8*)&Vb[addr] = v;
        }
    } else {
        u16* dst = (sel == 0) ? Qb : Kb;
        float invf[4];
#pragma unroll
        for (int p = 0; p < 4; ++p)
            invf[p] = expf(-0.14391156831212787f * (float)(dd + 2 * p));
#pragma unroll
        for (int i = 0; i < 8; ++i) {
            int nn = nn0 + i;
            float fn = (float)nn;
            ushort8 o;
#pragma unroll
            for (int p = 0; p < 4; ++p) {
                float ang = fn * invf[p];
                float sv = sinf(ang), cv = cosf(ang);
                float e0 = acc[i][2 * p]     * scl;
                float e1 = acc[i][2 * p + 1] * scl;
                o[2 * p]     = f2bf(e0 * cv - e1 * sv);
                o[2 * p + 1] = f2bf(e1 * cv + e0 * sv);
            }
            size_t base = (((size_t)(bi * NH + h)) * NSEQ + nn) * HD + dd;
            *(ushort8*)&dst[base] = o;
        }
    }
}

// ---------------------------------------------------------------------------
// Kernel 2: flash attention, bf16 MFMA (16x16x32). 4 waves x 16 q-rows per
// WG, 64-key tiles. LDS stride 72 bf16 (+8 pad -> 2-way conflicts, free).
// Writes AO in bf16 (proj GEMM consumes it via MFMA).
// ---------------------------------------------------------------------------
#define LSTR 72

__global__ __launch_bounds__(256)
void attn_kernel(const u16* __restrict__ Qb, const u16* __restrict__ Kb,
                 const u16* __restrict__ Vt, u16* __restrict__ AO)
{
    __shared__ u16 Qs[64 * LSTR];
    __shared__ u16 Ks[64 * LSTR];
    __shared__ u16 Vs[64 * LSTR];   // [d][key]
    __shared__ u16 Ps[64 * LSTR];   // 4 waves x [16 qrows][64 keys]

    const int tid  = threadIdx.x;
    const int lane = tid & 63;
    const int wid  = tid >> 6;
    const int l15  = lane & 15;
    const int quad = lane >> 4;
    const int qt = blockIdx.x;      // 0..31
    const int bh = blockIdx.y;      // 0..23

    const u16* Qg = Qb + ((size_t)bh * NSEQ + qt * 64) * HD;
    const u16* Kg = Kb + (size_t)bh * NSEQ * HD;
    const u16* Vg = Vt + (size_t)bh * HD * NSEQ;   // [64][2048]

    // stage Q (64 rows x 64 bf16)
#pragma unroll
    for (int it = 0; it < 2; ++it) {
        int idx = tid + 256 * it;
        int row = idx >> 3, c8 = (idx & 7) << 3;
        *(uint4*)&Qs[row * LSTR + c8] = *(const uint4*)&Qg[row * HD + c8];
    }
    __syncthreads();

    // A-fragments of Q are loop-invariant: load once
    bf16x8 aq[2];
#pragma unroll
    for (int k = 0; k < 2; ++k)
        aq[k] = *(const bf16x8*)&Qs[(wid * 16 + l15) * LSTR + quad * 8 + 32 * k];

    float m_i[4], l_i[4];
    f32x4 O[4];
#pragma unroll
    for (int r = 0; r < 4; ++r) { m_i[r] = -1e30f; l_i[r] = 0.f; }
#pragma unroll
    for (int t = 0; t < 4; ++t) O[t] = (f32x4){0.f, 0.f, 0.f, 0.f};

    u16* Pw = Ps + wid * 16 * LSTR;

    for (int kt = 0; kt < NSEQ / 64; ++kt) {
        __syncthreads();   // previous iteration's frag reads done
#pragma unroll
        for (int it = 0; it < 2; ++it) {
            int idx = tid + 256 * it;
            int row = idx >> 3, c8 = (idx & 7) << 3;
            *(uint4*)&Ks[row * LSTR + c8] =
                *(const uint4*)&Kg[(size_t)(kt * 64 + row) * HD + c8];
            *(uint4*)&Vs[row * LSTR + c8] =
                *(const uint4*)&Vg[(size_t)row * NSEQ + kt * 64 + c8];
        }
        __syncthreads();

        // S = Q . K^T : 4 col-tiles x 2 k-steps
        f32x4 sacc[4];
#pragma unroll
        for (int c = 0; c < 4; ++c) sacc[c] = (f32x4){0.f, 0.f, 0.f, 0.f};
#pragma unroll
        for (int k = 0; k < 2; ++k) {
#pragma unroll
            for (int c = 0; c < 4; ++c) {
                bf16x8 bk = *(const bf16x8*)
                    &Ks[(c * 16 + l15) * LSTR + quad * 8 + 32 * k];
                sacc[c] = __builtin_amdgcn_mfma_f32_16x16x32_bf16(
                    aq[k], bk, sacc[c], 0, 0, 0);
            }
        }

        // online softmax; lane holds rows quad*4+r, cols 16c+l15
        float alpha[4], p[4][4];
#pragma unroll
        for (int r = 0; r < 4; ++r) {
            float mt = fmaxf(fmaxf(sacc[0][r], sacc[1][r]),
                             fmaxf(sacc[2][r], sacc[3][r]));
            mt = fmaxf(mt, __shfl_xor(mt, 1));
            mt = fmaxf(mt, __shfl_xor(mt, 2));
            mt = fmaxf(mt, __shfl_xor(mt, 4));
            mt = fmaxf(mt, __shfl_xor(mt, 8));
            float mn = fmaxf(m_i[r], mt);
            alpha[r] = __expf(m_i[r] - mn);
            m_i[r] = mn;
            float rs = 0.f;
#pragma unroll
            for (int c = 0; c < 4; ++c) {
                float pv = __expf(sacc[c][r] - mn);
                p[c][r] = pv;
                rs += pv;
            }
            rs += __shfl_xor(rs, 1);
            rs += __shfl_xor(rs, 2);
            rs += __shfl_xor(rs, 4);
            rs += __shfl_xor(rs, 8);
            l_i[r] = l_i[r] * alpha[r] + rs;
        }

        // P -> wave-private LDS (bf16, row-major [16][LSTR])
#pragma unroll
        for (int c = 0; c < 4; ++c)
#pragma unroll
            for (int r = 0; r < 4; ++r)
                Pw[(quad * 4 + r) * LSTR + c * 16 + l15] = f2bf(p[c][r]);

        // rescale O
#pragma unroll
        for (int t = 0; t < 4; ++t)
#pragma unroll
            for (int r = 0; r < 4; ++r) O[t][r] *= alpha[r];

        // O += P . V : A = P rows, B = Vt (d-major)
#pragma unroll
        for (int k = 0; k < 2; ++k) {
            bf16x8 ap = *(const bf16x8*)&Pw[l15 * LSTR + quad * 8 + 32 * k];
#pragma unroll
            for (int t = 0; t < 4; ++t) {
                bf16x8 bv = *(const bf16x8*)
                    &Vs[(t * 16 + l15) * LSTR + quad * 8 + 32 * k];
                O[t] = __builtin_amdgcn_mfma_f32_16x16x32_bf16(
                    ap, bv, O[t], 0, 0, 0);
            }
        }
    }

    // normalize, store bf16 to AO [B*N, C]
    const int b = bh / NH, h = bh % NH;
#pragma unroll
    for (int r = 0; r < 4; ++r) {
        float inv = 1.0f / l_i[r];
        size_t row = (size_t)b * NSEQ + qt * 64 + wid * 16 + quad * 4 + r;
#pragma unroll
        for (int t = 0; t < 4; ++t)
            AO[row * CDIM + h * HD + t * 16 + l15] = f2bf(O[t][r] * inv);
    }
}

// ---------------------------------------------------------------------------
// Kernel 3: out = AO @ Wproj^T + bias, bf16 MFMA. Tiles 128x128x64,
// 4 waves (2x2), each wave 64x64 via 4x4 MFMA 16x16x32 tiles.
// ---------------------------------------------------------------------------
__global__ __launch_bounds__(256, 1)
void proj_kernel(const u16* __restrict__ A, const u16* __restrict__ Wp,
                 const float* __restrict__ bias, float* __restrict__ out)
{
    __shared__ u16 As[128 * LSTR];
    __shared__ u16 Bs[128 * LSTR];
    const int tid  = threadIdx.x;
    const int lane = tid & 63;
    const int wid  = tid >> 6;
    const int l15  = lane & 15;
    const int quad = lane >> 4;
    const int wr = wid >> 1, wc = wid & 1;
    const int m0 = blockIdx.x * 128;
    const int n0 = blockIdx.y * 128;

    f32x4 acc[4][4];
#pragma unroll
    for (int mi = 0; mi < 4; ++mi)
#pragma unroll
        for (int ni = 0; ni < 4; ++ni)
            acc[mi][ni] = (f32x4){0.f, 0.f, 0.f, 0.f};

    for (int kt = 0; kt < CDIM; kt += 64) {
        __syncthreads();
#pragma unroll
        for (int it = 0; it < 4; ++it) {
            int idx = tid + 256 * it;
            int row = idx >> 3, c8 = (idx & 7) << 3;
            *(uint4*)&As[row * LSTR + c8] =
                *(const uint4*)&A[(size_t)(m0 + row) * CDIM + kt + c8];
            *(uint4*)&Bs[row * LSTR + c8] =
                *(const uint4*)&Wp[(size_t)(n0 + row) * CDIM + kt + c8];
        }
        __syncthreads();
#pragma unroll
        for (int k = 0; k < 2; ++k) {
            bf16x8 af[4], bf[4];
#pragma unroll
            for (int mi = 0; mi < 4; ++mi)
                af[mi] = *(const bf16x8*)
                    &As[(wr * 64 + mi * 16 + l15) * LSTR + quad * 8 + 32 * k];
#pragma unroll
            for (int ni = 0; ni < 4; ++ni)
                bf[ni] = *(const bf16x8*)
                    &Bs[(wc * 64 + ni * 16 + l15) * LSTR + quad * 8 + 32 * k];
#pragma unroll
            for (int mi = 0; mi < 4; ++mi)
#pragma unroll
                for (int ni = 0; ni < 4; ++ni)
                    acc[mi][ni] = __builtin_amdgcn_mfma_f32_16x16x32_bf16(
                        af[mi], bf[ni], acc[mi][ni], 0, 0, 0);
        }
    }

    // epilogue: C/D col=lane&15, row=quad*4+r; add bias, fp32 store
#pragma unroll
    for (int ni = 0; ni < 4; ++ni) {
        int col = n0 + wc * 64 + ni * 16 + l15;
        float bb = bias[col];
#pragma unroll
        for (int mi = 0; mi < 4; ++mi) {
            int row = m0 + wr * 64 + mi * 16 + quad * 4;
#pragma unroll
            for (int r = 0; r < 4; ++r)
                out[(size_t)(row + r) * CDIM + col] = acc[mi][ni][r] + bb;
        }
    }
}

// ---------------------------------------------------------------------------
extern "C" void kernel_launch(void* const* d_in, const int* in_sizes, int n_in,
                              void* d_out, int out_size, void* d_ws,
                              size_t ws_size, hipStream_t stream)
{
    const float* X     = (const float*)d_in[0];   // [2, 2048, 768]
    const float* Wqkv  = (const float*)d_in[1];   // [2304, 768]
    const float* Wproj = (const float*)d_in[2];   // [768, 768]
    const float* bias  = (const float*)d_in[3];   // [768]
    float* out = (float*)d_out;                   // [2, 2048, 768]

    const size_t per_buf = (size_t)NB * NH * NSEQ * HD;  // 3145728 elems
    u16* Qb  = (u16*)d_ws;
    u16* Kb  = Qb + per_buf;
    u16* Vb  = Kb + per_buf;                      // [B,H,64,N]
    u16* AOb = Vb + per_buf;                      // [4096, 768] bf16
    u16* Wpb = AOb + per_buf;                     // [768, 768] bf16

    wconv_kernel<<<dim3(CDIM * CDIM / 1024), 256, 0, stream>>>(Wproj, Wpb);
    qkv_rope_kernel<<<dim3(32, 18), 256, 0, stream>>>(X, Wqkv, Qb, Kb, Vb);
    attn_kernel<<<dim3(32, 24), 256, 0, stream>>>(Qb, Kb, Vb, AOb);
    proj_kernel<<<dim3(32, 6), 256, 0, stream>>>(AOb, Wpb, bias, out);
}

// Round 4
// 295.641 us; speedup vs baseline: 8.2601x; 7.9927x over previous
//
#include <hip/hip_runtime.h>
#include <math.h>

#define NSEQ 2048
#define CDIM 768
#define NH   12
#define HD   64
#define NB   2

typedef unsigned short u16;
typedef __attribute__((ext_vector_type(8))) short bf16x8;   // 8 bf16 = 4 VGPRs
typedef __attribute__((ext_vector_type(4))) float f32x4;
typedef __attribute__((ext_vector_type(4))) unsigned short ushort4v;

// fp32 -> bf16 round-to-nearest-even (no NaN inputs here)
__device__ __forceinline__ u16 f2bf(float x) {
    unsigned int u = __float_as_uint(x);
    u += 0x7fffu + ((u >> 16) & 1u);
    return (u16)(u >> 16);
}
__device__ __forceinline__ float bf2f(u16 h) {
    return __uint_as_float((unsigned int)h << 16);
}

// ---------------------------------------------------------------------------
// Kernel 0a: fp32 -> (hi, lo) bf16 split. x ~= hi + lo to ~16 mantissa bits.
// 4 elems/thread, grid covers exactly n/1024 blocks.
// ---------------------------------------------------------------------------
__global__ __launch_bounds__(256)
void split_kernel(const float* __restrict__ src, u16* __restrict__ hi,
                  u16* __restrict__ lo)
{
    int i = (blockIdx.x * 256 + threadIdx.x) * 4;
    float4 v = *(const float4*)&src[i];
    ushort4v h, l;
    h.x = f2bf(v.x); l.x = f2bf(v.x - bf2f(h.x));
    h.y = f2bf(v.y); l.y = f2bf(v.y - bf2f(h.y));
    h.z = f2bf(v.z); l.z = f2bf(v.z - bf2f(h.z));
    h.w = f2bf(v.w); l.w = f2bf(v.w - bf2f(h.w));
    *(ushort4v*)&hi[i] = h;
    *(ushort4v*)&lo[i] = l;
}

// ---------------------------------------------------------------------------
// Kernel 0b: Wproj fp32 -> bf16 (single precision is enough for proj)
// ---------------------------------------------------------------------------
__global__ __launch_bounds__(256)
void wconv_kernel(const float* __restrict__ W, u16* __restrict__ Wb)
{
    int i = (blockIdx.x * 256 + threadIdx.x) * 4;
    float4 v = *(const float4*)&W[i];
    ushort4v o;
    o.x = f2bf(v.x); o.y = f2bf(v.y); o.z = f2bf(v.z); o.w = f2bf(v.w);
    *(ushort4v*)&Wb[i] = o;
}

// ---------------------------------------------------------------------------
// Kernel 1: qkv = X @ Wqkv^T via bf16x3 split MFMA (acc += ah*bh + ah*bl +
// al*bh; lo*lo dropped -> rel err ~2^-17). Tiles 128x128x32, 4 waves 2x2,
// each wave 64x64 via 4x4 MFMA 16x16x32. Fused scale (q), RoPE (q,k) in
// MFMA C-layout (pair partner = lane^1 shuffle), head transpose, bf16 out.
// Q,K: [B,H,N,64]; V: [B,H,64,N] (transposed for attn B-fragments).
// R2/R3 post-mortem: the fp32-VALU version pinned at VGPR=60 and spilled
// 8.4 GB to scratch; MFMA structure (proven in attn/proj) avoids it.
// ---------------------------------------------------------------------------
#define KSTR 40   // LDS row stride (u16) for 32-wide K tiles (+8 pad)

__global__ __launch_bounds__(256)
void qkv_mfma_kernel(const u16* __restrict__ Xhi, const u16* __restrict__ Xlo,
                     const u16* __restrict__ Whi, const u16* __restrict__ Wlo,
                     u16* __restrict__ Qb, u16* __restrict__ Kb,
                     u16* __restrict__ Vb)
{
    __shared__ __align__(16) u16 Ahi[128 * KSTR];
    __shared__ __align__(16) u16 Alo[128 * KSTR];
    __shared__ __align__(16) u16 Bhi[128 * KSTR];
    __shared__ __align__(16) u16 Blo[128 * KSTR];

    const int tid  = threadIdx.x;
    const int lane = tid & 63;
    const int wid  = tid >> 6;
    const int l15  = lane & 15;
    const int quad = lane >> 4;
    const int wr = wid >> 1, wc = wid & 1;
    const int m0 = blockIdx.x * 128;      // token-row tile
    const int n0 = blockIdx.y * 128;      // qkv-feature tile (0..2303)

    f32x4 acc[4][4];
#pragma unroll
    for (int mi = 0; mi < 4; ++mi)
#pragma unroll
        for (int ni = 0; ni < 4; ++ni)
            acc[mi][ni] = (f32x4){0.f, 0.f, 0.f, 0.f};

    for (int kt = 0; kt < CDIM; kt += 32) {
        __syncthreads();
        // stage 4 bufs of 128x32 u16; uint4 = 8 bf16; 2 uint4/thread/buf
#pragma unroll
        for (int it = 0; it < 2; ++it) {
            int idx = tid + 256 * it;          // 0..511
            int row = idx >> 2, c8 = (idx & 3) << 3;
            size_t ga = (size_t)(m0 + row) * CDIM + kt + c8;
            size_t gb = (size_t)(n0 + row) * CDIM + kt + c8;
            *(uint4*)&Ahi[row * KSTR + c8] = *(const uint4*)&Xhi[ga];
            *(uint4*)&Alo[row * KSTR + c8] = *(const uint4*)&Xlo[ga];
            *(uint4*)&Bhi[row * KSTR + c8] = *(const uint4*)&Whi[gb];
            *(uint4*)&Blo[row * KSTR + c8] = *(const uint4*)&Wlo[gb];
        }
        __syncthreads();

        bf16x8 ah[4], al[4], bh[4], bl[4];
#pragma unroll
        for (int mi = 0; mi < 4; ++mi) {
            int off = (wr * 64 + mi * 16 + l15) * KSTR + quad * 8;
            ah[mi] = *(const bf16x8*)&Ahi[off];
            al[mi] = *(const bf16x8*)&Alo[off];
        }
#pragma unroll
        for (int ni = 0; ni < 4; ++ni) {
            int off = (wc * 64 + ni * 16 + l15) * KSTR + quad * 8;
            bh[ni] = *(const bf16x8*)&Bhi[off];
            bl[ni] = *(const bf16x8*)&Blo[off];
        }
#pragma unroll
        for (int mi = 0; mi < 4; ++mi)
#pragma unroll
            for (int ni = 0; ni < 4; ++ni) {
                acc[mi][ni] = __builtin_amdgcn_mfma_f32_16x16x32_bf16(
                    ah[mi], bh[ni], acc[mi][ni], 0, 0, 0);
                acc[mi][ni] = __builtin_amdgcn_mfma_f32_16x16x32_bf16(
                    ah[mi], bl[ni], acc[mi][ni], 0, 0, 0);
                acc[mi][ni] = __builtin_amdgcn_mfma_f32_16x16x32_bf16(
                    al[mi], bh[ni], acc[mi][ni], 0, 0, 0);
            }
    }

    // Epilogue in MFMA C-layout: row = wr*64+mi*16+quad*4+r (token),
    // col = wc*64+ni*16+l15 (feature). Wave's 64 cols = exactly one head.
    const int bi      = m0 >> 11;                // batch (tiles don't straddle)
    const int nbase   = (m0 & 2047) + wr * 64;
    const int colbase = n0 + wc * 64;            // 64-aligned
    const int sel     = colbase / CDIM;          // 0=q,1=k,2=v (wave-uniform)
    const int h       = (colbase % CDIM) >> 6;   // head (wave-uniform)

    if (sel == 2) {
        u16* dst = Vb + (size_t)(bi * NH + h) * HD * NSEQ;   // [64][2048]
#pragma unroll
        for (int ni = 0; ni < 4; ++ni) {
            int dd = ni * 16 + l15;
#pragma unroll
            for (int mi = 0; mi < 4; ++mi)
#pragma unroll
                for (int r = 0; r < 4; ++r) {
                    int n = nbase + mi * 16 + quad * 4 + r;
                    dst[(size_t)dd * NSEQ + n] = f2bf(acc[mi][ni][r]);
                }
        }
    } else {
        u16* dst = ((sel == 0) ? Qb : Kb) + (size_t)(bi * NH + h) * NSEQ * HD;
        const float scl = (sel == 0) ? 0.125f : 1.0f;   // d^-0.5, q only
#pragma unroll
        for (int ni = 0; ni < 4; ++ni) {
            int dd = ni * 16 + l15;
            // inv_freq = 10000^(-(dd&~1)/64); precise expf to track numpy
            float invf = expf(-0.14391156831212787f * (float)(dd & ~1));
#pragma unroll
            for (int mi = 0; mi < 4; ++mi) {
                f32x4 val = acc[mi][ni];
#pragma unroll
                for (int r = 0; r < 4; ++r) {
                    float e = val[r] * scl;
                    float p = __shfl_xor(e, 1);    // pair partner (col^1)
                    int n = nbase + mi * 16 + quad * 4 + r;
                    float sv, cv;
                    __sincosf((float)n * invf, &sv, &cv);
                    float o = (dd & 1) ? (e * cv + p * sv)
                                       : (e * cv - p * sv);
                    dst[(size_t)n * HD + dd] = f2bf(o);
                }
            }
        }
    }
}

// ---------------------------------------------------------------------------
// Kernel 2: flash attention, bf16 MFMA (16x16x32). 4 waves x 16 q-rows per
// WG, 64-key tiles. LDS stride 72 bf16 (+8 pad -> 2-way conflicts, free).
// Writes AO in bf16 (proj GEMM consumes it via MFMA).
// ---------------------------------------------------------------------------
#define LSTR 72

__global__ __launch_bounds__(256)
void attn_kernel(const u16* __restrict__ Qb, const u16* __restrict__ Kb,
                 const u16* __restrict__ Vt, u16* __restrict__ AO)
{
    __shared__ __align__(16) u16 Qs[64 * LSTR];
    __shared__ __align__(16) u16 Ks[64 * LSTR];
    __shared__ __align__(16) u16 Vs[64 * LSTR];   // [d][key]
    __shared__ __align__(16) u16 Ps[64 * LSTR];   // 4 waves x [16 qrows][64]

    const int tid  = threadIdx.x;
    const int lane = tid & 63;
    const int wid  = tid >> 6;
    const int l15  = lane & 15;
    const int quad = lane >> 4;
    const int qt = blockIdx.x;      // 0..31
    const int bh = blockIdx.y;      // 0..23

    const u16* Qg = Qb + ((size_t)bh * NSEQ + qt * 64) * HD;
    const u16* Kg = Kb + (size_t)bh * NSEQ * HD;
    const u16* Vg = Vt + (size_t)bh * HD * NSEQ;   // [64][2048]

    // stage Q (64 rows x 64 bf16)
#pragma unroll
    for (int it = 0; it < 2; ++it) {
        int idx = tid + 256 * it;
        int row = idx >> 3, c8 = (idx & 7) << 3;
        *(uint4*)&Qs[row * LSTR + c8] = *(const uint4*)&Qg[row * HD + c8];
    }
    __syncthreads();

    // A-fragments of Q are loop-invariant: load once
    bf16x8 aq[2];
#pragma unroll
    for (int k = 0; k < 2; ++k)
        aq[k] = *(const bf16x8*)&Qs[(wid * 16 + l15) * LSTR + quad * 8 + 32 * k];

    float m_i[4], l_i[4];
    f32x4 O[4];
#pragma unroll
    for (int r = 0; r < 4; ++r) { m_i[r] = -1e30f; l_i[r] = 0.f; }
#pragma unroll
    for (int t = 0; t < 4; ++t) O[t] = (f32x4){0.f, 0.f, 0.f, 0.f};

    u16* Pw = Ps + wid * 16 * LSTR;

    for (int kt = 0; kt < NSEQ / 64; ++kt) {
        __syncthreads();   // previous iteration's frag reads done
#pragma unroll
        for (int it = 0; it < 2; ++it) {
            int idx = tid + 256 * it;
            int row = idx >> 3, c8 = (idx & 7) << 3;
            *(uint4*)&Ks[row * LSTR + c8] =
                *(const uint4*)&Kg[(size_t)(kt * 64 + row) * HD + c8];
            *(uint4*)&Vs[row * LSTR + c8] =
                *(const uint4*)&Vg[(size_t)row * NSEQ + kt * 64 + c8];
        }
        __syncthreads();

        // S = Q . K^T : 4 col-tiles x 2 k-steps
        f32x4 sacc[4];
#pragma unroll
        for (int c = 0; c < 4; ++c) sacc[c] = (f32x4){0.f, 0.f, 0.f, 0.f};
#pragma unroll
        for (int k = 0; k < 2; ++k) {
#pragma unroll
            for (int c = 0; c < 4; ++c) {
                bf16x8 bk = *(const bf16x8*)
                    &Ks[(c * 16 + l15) * LSTR + quad * 8 + 32 * k];
                sacc[c] = __builtin_amdgcn_mfma_f32_16x16x32_bf16(
                    aq[k], bk, sacc[c], 0, 0, 0);
            }
        }

        // online softmax; lane holds rows quad*4+r, cols 16c+l15
        float alpha[4], p[4][4];
#pragma unroll
        for (int r = 0; r < 4; ++r) {
            float mt = fmaxf(fmaxf(sacc[0][r], sacc[1][r]),
                             fmaxf(sacc[2][r], sacc[3][r]));
            mt = fmaxf(mt, __shfl_xor(mt, 1));
            mt = fmaxf(mt, __shfl_xor(mt, 2));
            mt = fmaxf(mt, __shfl_xor(mt, 4));
            mt = fmaxf(mt, __shfl_xor(mt, 8));
            float mn = fmaxf(m_i[r], mt);
            alpha[r] = __expf(m_i[r] - mn);
            m_i[r] = mn;
            float rs = 0.f;
#pragma unroll
            for (int c = 0; c < 4; ++c) {
                float pv = __expf(sacc[c][r] - mn);
                p[c][r] = pv;
                rs += pv;
            }
            rs += __shfl_xor(rs, 1);
            rs += __shfl_xor(rs, 2);
            rs += __shfl_xor(rs, 4);
            rs += __shfl_xor(rs, 8);
            l_i[r] = l_i[r] * alpha[r] + rs;
        }

        // P -> wave-private LDS (bf16, row-major [16][LSTR])
#pragma unroll
        for (int c = 0; c < 4; ++c)
#pragma unroll
            for (int r = 0; r < 4; ++r)
                Pw[(quad * 4 + r) * LSTR + c * 16 + l15] = f2bf(p[c][r]);

        // rescale O
#pragma unroll
        for (int t = 0; t < 4; ++t)
#pragma unroll
            for (int r = 0; r < 4; ++r) O[t][r] *= alpha[r];

        // O += P . V : A = P rows, B = Vt (d-major)
#pragma unroll
        for (int k = 0; k < 2; ++k) {
            bf16x8 ap = *(const bf16x8*)&Pw[l15 * LSTR + quad * 8 + 32 * k];
#pragma unroll
            for (int t = 0; t < 4; ++t) {
                bf16x8 bv = *(const bf16x8*)
                    &Vs[(t * 16 + l15) * LSTR + quad * 8 + 32 * k];
                O[t] = __builtin_amdgcn_mfma_f32_16x16x32_bf16(
                    ap, bv, O[t], 0, 0, 0);
            }
        }
    }

    // normalize, store bf16 to AO [B*N, C]
    const int b = bh / NH, h = bh % NH;
#pragma unroll
    for (int r = 0; r < 4; ++r) {
        float inv = 1.0f / l_i[r];
        size_t row = (size_t)b * NSEQ + qt * 64 + wid * 16 + quad * 4 + r;
#pragma unroll
        for (int t = 0; t < 4; ++t)
            AO[row * CDIM + h * HD + t * 16 + l15] = f2bf(O[t][r] * inv);
    }
}

// ---------------------------------------------------------------------------
// Kernel 3: out = AO @ Wproj^T + bias, bf16 MFMA. Tiles 128x128x64,
// 4 waves (2x2), each wave 64x64 via 4x4 MFMA 16x16x32 tiles.
// ---------------------------------------------------------------------------
__global__ __launch_bounds__(256)
void proj_kernel(const u16* __restrict__ A, const u16* __restrict__ Wp,
                 const float* __restrict__ bias, float* __restrict__ out)
{
    __shared__ __align__(16) u16 As[128 * LSTR];
    __shared__ __align__(16) u16 Bs[128 * LSTR];
    const int tid  = threadIdx.x;
    const int lane = tid & 63;
    const int wid  = tid >> 6;
    const int l15  = lane & 15;
    const int quad = lane >> 4;
    const int wr = wid >> 1, wc = wid & 1;
    const int m0 = blockIdx.x * 128;
    const int n0 = blockIdx.y * 128;

    f32x4 acc[4][4];
#pragma unroll
    for (int mi = 0; mi < 4; ++mi)
#pragma unroll
        for (int ni = 0; ni < 4; ++ni)
            acc[mi][ni] = (f32x4){0.f, 0.f, 0.f, 0.f};

    for (int kt = 0; kt < CDIM; kt += 64) {
        __syncthreads();
#pragma unroll
        for (int it = 0; it < 4; ++it) {
            int idx = tid + 256 * it;
            int row = idx >> 3, c8 = (idx & 7) << 3;
            *(uint4*)&As[row * LSTR + c8] =
                *(const uint4*)&A[(size_t)(m0 + row) * CDIM + kt + c8];
            *(uint4*)&Bs[row * LSTR + c8] =
                *(const uint4*)&Wp[(size_t)(n0 + row) * CDIM + kt + c8];
        }
        __syncthreads();
#pragma unroll
        for (int k = 0; k < 2; ++k) {
            bf16x8 af[4], bf[4];
#pragma unroll
            for (int mi = 0; mi < 4; ++mi)
                af[mi] = *(const bf16x8*)
                    &As[(wr * 64 + mi * 16 + l15) * LSTR + quad * 8 + 32 * k];
#pragma unroll
            for (int ni = 0; ni < 4; ++ni)
                bf[ni] = *(const bf16x8*)
                    &Bs[(wc * 64 + ni * 16 + l15) * LSTR + quad * 8 + 32 * k];
#pragma unroll
            for (int mi = 0; mi < 4; ++mi)
#pragma unroll
                for (int ni = 0; ni < 4; ++ni)
                    acc[mi][ni] = __builtin_amdgcn_mfma_f32_16x16x32_bf16(
                        af[mi], bf[ni], acc[mi][ni], 0, 0, 0);
        }
    }

    // epilogue: C/D col=lane&15, row=quad*4+r; add bias, fp32 store
#pragma unroll
    for (int ni = 0; ni < 4; ++ni) {
        int col = n0 + wc * 64 + ni * 16 + l15;
        float bb = bias[col];
#pragma unroll
        for (int mi = 0; mi < 4; ++mi) {
            int row = m0 + wr * 64 + mi * 16 + quad * 4;
#pragma unroll
            for (int r = 0; r < 4; ++r)
                out[(size_t)(row + r) * CDIM + col] = acc[mi][ni][r] + bb;
        }
    }
}

// ---------------------------------------------------------------------------
extern "C" void kernel_launch(void* const* d_in, const int* in_sizes, int n_in,
                              void* d_out, int out_size, void* d_ws,
                              size_t ws_size, hipStream_t stream)
{
    const float* X     = (const float*)d_in[0];   // [2, 2048, 768]
    const float* Wqkv  = (const float*)d_in[1];   // [2304, 768]
    const float* Wproj = (const float*)d_in[2];   // [768, 768]
    const float* bias  = (const float*)d_in[3];   // [768]
    float* out = (float*)d_out;                   // [2, 2048, 768]

    const size_t per_buf = (size_t)NB * NH * NSEQ * HD;   // 3145728
    const size_t xw_sz   = per_buf;                       // 4096*768
    const size_t wq_sz   = (size_t)3 * CDIM * CDIM;       // 2304*768
    u16* Qb  = (u16*)d_ws;
    u16* Kb  = Qb + per_buf;
    u16* Vb  = Kb + per_buf;                      // [B,H,64,N]
    u16* AOb = Vb + per_buf;                      // [4096, 768] bf16
    u16* Wpb = AOb + per_buf;                     // [768, 768] bf16
    u16* Xhi = Wpb + (size_t)CDIM * CDIM;
    u16* Xlo = Xhi + xw_sz;
    u16* Whi = Xlo + xw_sz;
    u16* Wlo = Whi + wq_sz;

    split_kernel<<<dim3(xw_sz / 1024), 256, 0, stream>>>(X, Xhi, Xlo);
    split_kernel<<<dim3(wq_sz / 1024), 256, 0, stream>>>(Wqkv, Whi, Wlo);
    wconv_kernel<<<dim3(CDIM * CDIM / 1024), 256, 0, stream>>>(Wproj, Wpb);
    qkv_mfma_kernel<<<dim3(32, 18), 256, 0, stream>>>(Xhi, Xlo, Whi, Wlo,
                                                      Qb, Kb, Vb);
    attn_kernel<<<dim3(32, 24), 256, 0, stream>>>(Qb, Kb, Vb, AOb);
    proj_kernel<<<dim3(32, 6), 256, 0, stream>>>(AOb, Wpb, bias, out);
}

// Round 5
// 204.146 us; speedup vs baseline: 11.9622x; 1.4482x over previous
//
#include <hip/hip_runtime.h>
#include <math.h>

#define NSEQ 2048
#define CDIM 768
#define NH   12
#define HD   64
#define NB   2

typedef unsigned short u16;
typedef __attribute__((ext_vector_type(8))) short bf16x8;   // 8 bf16 = 4 VGPRs
typedef __attribute__((ext_vector_type(4))) float f32x4;
typedef __attribute__((ext_vector_type(4))) unsigned short ushort4v;

// fp32 -> bf16 round-to-nearest-even (no NaN inputs here)
__device__ __forceinline__ u16 f2bf(float x) {
    unsigned int u = __float_as_uint(x);
    u += 0x7fffu + ((u >> 16) & 1u);
    return (u16)(u >> 16);
}
__device__ __forceinline__ float bf2f(u16 h) {
    return __uint_as_float((unsigned int)h << 16);
}

// ---------------------------------------------------------------------------
// Kernel 0a: fp32 -> (hi, lo) bf16 split. x ~= hi + lo to ~16 mantissa bits.
// ---------------------------------------------------------------------------
__global__ __launch_bounds__(256)
void split_kernel(const float* __restrict__ src, u16* __restrict__ hi,
                  u16* __restrict__ lo)
{
    int i = (blockIdx.x * 256 + threadIdx.x) * 4;
    float4 v = *(const float4*)&src[i];
    ushort4v h, l;
    h.x = f2bf(v.x); l.x = f2bf(v.x - bf2f(h.x));
    h.y = f2bf(v.y); l.y = f2bf(v.y - bf2f(h.y));
    h.z = f2bf(v.z); l.z = f2bf(v.z - bf2f(h.z));
    h.w = f2bf(v.w); l.w = f2bf(v.w - bf2f(h.w));
    *(ushort4v*)&hi[i] = h;
    *(ushort4v*)&lo[i] = l;
}

// ---------------------------------------------------------------------------
// Kernel 0b: Wproj fp32 -> bf16
// ---------------------------------------------------------------------------
__global__ __launch_bounds__(256)
void wconv_kernel(const float* __restrict__ W, u16* __restrict__ Wb)
{
    int i = (blockIdx.x * 256 + threadIdx.x) * 4;
    float4 v = *(const float4*)&W[i];
    ushort4v o;
    o.x = f2bf(v.x); o.y = f2bf(v.y); o.z = f2bf(v.z); o.w = f2bf(v.w);
    *(ushort4v*)&Wb[i] = o;
}

// ---------------------------------------------------------------------------
// Kernel 1: qkv = X @ Wqkv^T via bf16x3 split MFMA. Tiles 128x128x32,
// 4 waves 2x2, wave 64x64 via 4x4 MFMA 16x16x32. Register-prefetch staging
// (R5): next k-tile's global loads issue after barrier-2 so HBM latency
// overlaps the 48 MFMAs instead of draining inside the barrier pair.
// Fused scale (q), RoPE (q,k) in C-layout, head transpose, bf16 out.
// ---------------------------------------------------------------------------
#define KSTR 40   // LDS row stride (u16) for 32-wide K tiles (+8 pad)

__global__ __launch_bounds__(256)
void qkv_mfma_kernel(const u16* __restrict__ Xhi, const u16* __restrict__ Xlo,
                     const u16* __restrict__ Whi, const u16* __restrict__ Wlo,
                     u16* __restrict__ Qb, u16* __restrict__ Kb,
                     u16* __restrict__ Vb)
{
    __shared__ __align__(16) u16 Ahi[128 * KSTR];
    __shared__ __align__(16) u16 Alo[128 * KSTR];
    __shared__ __align__(16) u16 Bhi[128 * KSTR];
    __shared__ __align__(16) u16 Blo[128 * KSTR];

    const int tid  = threadIdx.x;
    const int lane = tid & 63;
    const int wid  = tid >> 6;
    const int l15  = lane & 15;
    const int quad = lane >> 4;
    const int wr = wid >> 1, wc = wid & 1;
    const int m0 = blockIdx.x * 128;
    const int n0 = blockIdx.y * 128;

    // staging coords: 2 chunks/thread/buffer
    const int row0 = tid >> 2, c80 = (tid & 3) << 3;        // rows 0..63
    const int row1 = row0 + 64, c81 = c80;                  // rows 64..127

    f32x4 acc[4][4];
#pragma unroll
    for (int mi = 0; mi < 4; ++mi)
#pragma unroll
        for (int ni = 0; ni < 4; ++ni)
            acc[mi][ni] = (f32x4){0.f, 0.f, 0.f, 0.f};

    // preload kt=0
    uint4 pa0, pa1, pl0, pl1, pb0, pb1, pq0, pq1;
    {
        size_t ga0 = (size_t)(m0 + row0) * CDIM + c80;
        size_t ga1 = (size_t)(m0 + row1) * CDIM + c81;
        size_t gb0 = (size_t)(n0 + row0) * CDIM + c80;
        size_t gb1 = (size_t)(n0 + row1) * CDIM + c81;
        pa0 = *(const uint4*)&Xhi[ga0]; pa1 = *(const uint4*)&Xhi[ga1];
        pl0 = *(const uint4*)&Xlo[ga0]; pl1 = *(const uint4*)&Xlo[ga1];
        pb0 = *(const uint4*)&Whi[gb0]; pb1 = *(const uint4*)&Whi[gb1];
        pq0 = *(const uint4*)&Wlo[gb0]; pq1 = *(const uint4*)&Wlo[gb1];
    }

    for (int kt = 0; kt < CDIM; kt += 32) {
        __syncthreads();
        *(uint4*)&Ahi[row0 * KSTR + c80] = pa0;
        *(uint4*)&Ahi[row1 * KSTR + c81] = pa1;
        *(uint4*)&Alo[row0 * KSTR + c80] = pl0;
        *(uint4*)&Alo[row1 * KSTR + c81] = pl1;
        *(uint4*)&Bhi[row0 * KSTR + c80] = pb0;
        *(uint4*)&Bhi[row1 * KSTR + c81] = pb1;
        *(uint4*)&Blo[row0 * KSTR + c80] = pq0;
        *(uint4*)&Blo[row1 * KSTR + c81] = pq1;
        __syncthreads();

        if (kt + 32 < CDIM) {
            size_t ga0 = (size_t)(m0 + row0) * CDIM + kt + 32 + c80;
            size_t ga1 = (size_t)(m0 + row1) * CDIM + kt + 32 + c81;
            size_t gb0 = (size_t)(n0 + row0) * CDIM + kt + 32 + c80;
            size_t gb1 = (size_t)(n0 + row1) * CDIM + kt + 32 + c81;
            pa0 = *(const uint4*)&Xhi[ga0]; pa1 = *(const uint4*)&Xhi[ga1];
            pl0 = *(const uint4*)&Xlo[ga0]; pl1 = *(const uint4*)&Xlo[ga1];
            pb0 = *(const uint4*)&Whi[gb0]; pb1 = *(const uint4*)&Whi[gb1];
            pq0 = *(const uint4*)&Wlo[gb0]; pq1 = *(const uint4*)&Wlo[gb1];
        }

        bf16x8 ah[4], al[4];
#pragma unroll
        for (int mi = 0; mi < 4; ++mi) {
            int off = (wr * 64 + mi * 16 + l15) * KSTR + quad * 8;
            ah[mi] = *(const bf16x8*)&Ahi[off];
            al[mi] = *(const bf16x8*)&Alo[off];
        }
#pragma unroll
        for (int ni = 0; ni < 4; ++ni) {
            int off = (wc * 64 + ni * 16 + l15) * KSTR + quad * 8;
            bf16x8 bh = *(const bf16x8*)&Bhi[off];
            bf16x8 bl = *(const bf16x8*)&Blo[off];
#pragma unroll
            for (int mi = 0; mi < 4; ++mi) {
                acc[mi][ni] = __builtin_amdgcn_mfma_f32_16x16x32_bf16(
                    ah[mi], bh, acc[mi][ni], 0, 0, 0);
                acc[mi][ni] = __builtin_amdgcn_mfma_f32_16x16x32_bf16(
                    ah[mi], bl, acc[mi][ni], 0, 0, 0);
                acc[mi][ni] = __builtin_amdgcn_mfma_f32_16x16x32_bf16(
                    al[mi], bh, acc[mi][ni], 0, 0, 0);
            }
        }
    }

    // Epilogue in MFMA C-layout: row = wr*64+mi*16+quad*4+r (token),
    // col = wc*64+ni*16+l15 (feature). Wave's 64 cols = exactly one head.
    const int bi      = m0 >> 11;
    const int nbase   = (m0 & 2047) + wr * 64;
    const int colbase = n0 + wc * 64;
    const int sel     = colbase / CDIM;          // 0=q,1=k,2=v (wave-uniform)
    const int h       = (colbase % CDIM) >> 6;

    if (sel == 2) {
        u16* dst = Vb + (size_t)(bi * NH + h) * HD * NSEQ;   // [64][2048]
#pragma unroll
        for (int ni = 0; ni < 4; ++ni) {
            int dd = ni * 16 + l15;
#pragma unroll
            for (int mi = 0; mi < 4; ++mi)
#pragma unroll
                for (int r = 0; r < 4; ++r) {
                    int n = nbase + mi * 16 + quad * 4 + r;
                    dst[(size_t)dd * NSEQ + n] = f2bf(acc[mi][ni][r]);
                }
        }
    } else {
        u16* dst = ((sel == 0) ? Qb : Kb) + (size_t)(bi * NH + h) * NSEQ * HD;
        const float scl = (sel == 0) ? 0.125f : 1.0f;
#pragma unroll
        for (int ni = 0; ni < 4; ++ni) {
            int dd = ni * 16 + l15;
            float invf = expf(-0.14391156831212787f * (float)(dd & ~1));
#pragma unroll
            for (int mi = 0; mi < 4; ++mi) {
                f32x4 val = acc[mi][ni];
#pragma unroll
                for (int r = 0; r < 4; ++r) {
                    float e = val[r] * scl;
                    float p = __shfl_xor(e, 1);    // pair partner (col^1)
                    int n = nbase + mi * 16 + quad * 4 + r;
                    float sv, cv;
                    __sincosf((float)n * invf, &sv, &cv);
                    float o = (dd & 1) ? (e * cv + p * sv)
                                       : (e * cv - p * sv);
                    dst[(size_t)n * HD + dd] = f2bf(o);
                }
            }
        }
    }
}

// ---------------------------------------------------------------------------
// Kernel 2: flash attention, bf16 MFMA. R5 restructure:
//  - S^T orientation (A=K-frag, B=Q-frag): lane holds 16 keys of ONE q-row
//    -> softmax row-sums are in-lane; P-write packs 4 consecutive keys
//    (ds_write_b64 x4 instead of b16 x16).
//  - fixed-max softmax: |s| <= |q||k| ~ 8 (q pre-scaled by 1/8), so exp(s)
//    can't overflow; drop online max/alpha/rescale; l_i is a pure sum,
//    cross-lane-reduced ONCE after the loop.
//  - K/V staging register-prefetch; Q staged through Ps (saves 9 KB LDS).
// ---------------------------------------------------------------------------
#define LSTR 72

__global__ __launch_bounds__(256)
void attn_kernel(const u16* __restrict__ Qb, const u16* __restrict__ Kb,
                 const u16* __restrict__ Vt, u16* __restrict__ AO)
{
    __shared__ __align__(16) u16 Ks[64 * LSTR];
    __shared__ __align__(16) u16 Vs[64 * LSTR];   // [d][key]
    __shared__ __align__(16) u16 Ps[64 * LSTR];   // 4 waves x [16 qrows][64]

    const int tid  = threadIdx.x;
    const int lane = tid & 63;
    const int wid  = tid >> 6;
    const int l15  = lane & 15;
    const int quad = lane >> 4;
    const int qt = blockIdx.x;      // 0..31
    const int bh = blockIdx.y;      // 0..23

    const u16* Qg = Qb + ((size_t)bh * NSEQ + qt * 64) * HD;
    const u16* Kg = Kb + (size_t)bh * NSEQ * HD;
    const u16* Vg = Vt + (size_t)bh * HD * NSEQ;   // [64][2048]

    const int row0 = tid >> 3, c8 = (tid & 7) << 3;   // rows 0..31
    const int row1 = row0 + 32;

    // stage Q (64x64) through Ps, grab loop-invariant B-frags
    *(uint4*)&Ps[row0 * LSTR + c8] = *(const uint4*)&Qg[row0 * HD + c8];
    *(uint4*)&Ps[row1 * LSTR + c8] = *(const uint4*)&Qg[row1 * HD + c8];
    __syncthreads();
    bf16x8 aq[2];
#pragma unroll
    for (int k = 0; k < 2; ++k)
        aq[k] = *(const bf16x8*)&Ps[(wid * 16 + l15) * LSTR + quad * 8 + 32 * k];
    // (no barrier needed: each wave reads only its own q-rows region and
    //  only this wave writes its Pw region later)

    float l_part = 0.f;       // per-lane partial: qrow = l15, 16 keys/tile
    f32x4 O[4];
#pragma unroll
    for (int t = 0; t < 4; ++t) O[t] = (f32x4){0.f, 0.f, 0.f, 0.f};

    u16* Pw = Ps + wid * 16 * LSTR;

    // preload kt=0 K/V
    uint4 k0, k1, v0, v1;
    k0 = *(const uint4*)&Kg[(size_t)row0 * HD + c8];
    k1 = *(const uint4*)&Kg[(size_t)row1 * HD + c8];
    v0 = *(const uint4*)&Vg[(size_t)row0 * NSEQ + c8];
    v1 = *(const uint4*)&Vg[(size_t)row1 * NSEQ + c8];

    for (int kt = 0; kt < NSEQ / 64; ++kt) {
        __syncthreads();   // previous iteration's frag reads done
        *(uint4*)&Ks[row0 * LSTR + c8] = k0;
        *(uint4*)&Ks[row1 * LSTR + c8] = k1;
        *(uint4*)&Vs[row0 * LSTR + c8] = v0;
        *(uint4*)&Vs[row1 * LSTR + c8] = v1;
        __syncthreads();

        if (kt + 1 < NSEQ / 64) {
            k0 = *(const uint4*)&Kg[(size_t)((kt + 1) * 64 + row0) * HD + c8];
            k1 = *(const uint4*)&Kg[(size_t)((kt + 1) * 64 + row1) * HD + c8];
            v0 = *(const uint4*)&Vg[(size_t)row0 * NSEQ + (kt + 1) * 64 + c8];
            v1 = *(const uint4*)&Vg[(size_t)row1 * NSEQ + (kt + 1) * 64 + c8];
        }

        // S^T = K . Q^T : D[key=mt*16+quad*4+r][qrow=l15]
        f32x4 sacc[4];
#pragma unroll
        for (int mt = 0; mt < 4; ++mt) sacc[mt] = (f32x4){0.f, 0.f, 0.f, 0.f};
#pragma unroll
        for (int k = 0; k < 2; ++k) {
#pragma unroll
            for (int mt = 0; mt < 4; ++mt) {
                bf16x8 ak = *(const bf16x8*)
                    &Ks[(mt * 16 + l15) * LSTR + quad * 8 + 32 * k];
                sacc[mt] = __builtin_amdgcn_mfma_f32_16x16x32_bf16(
                    ak, aq[k], sacc[mt], 0, 0, 0);
            }
        }

        // fixed-max softmax, all in-lane; pack 4 keys -> one b64 write
#pragma unroll
        for (int mt = 0; mt < 4; ++mt) {
            float e0 = __expf(sacc[mt][0]);
            float e1 = __expf(sacc[mt][1]);
            float e2 = __expf(sacc[mt][2]);
            float e3 = __expf(sacc[mt][3]);
            l_part += (e0 + e1) + (e2 + e3);
            ushort4v pk;
            pk.x = f2bf(e0); pk.y = f2bf(e1);
            pk.z = f2bf(e2); pk.w = f2bf(e3);
            *(ushort4v*)&Pw[l15 * LSTR + mt * 16 + quad * 4] = pk;
        }

        // O += P . V : A = P rows (m=qrow=l15 frag), B = Vt (d-major)
#pragma unroll
        for (int k = 0; k < 2; ++k) {
            bf16x8 ap = *(const bf16x8*)&Pw[l15 * LSTR + quad * 8 + 32 * k];
#pragma unroll
            for (int t = 0; t < 4; ++t) {
                bf16x8 bv = *(const bf16x8*)
                    &Vs[(t * 16 + l15) * LSTR + quad * 8 + 32 * k];
                O[t] = __builtin_amdgcn_mfma_f32_16x16x32_bf16(
                    ap, bv, O[t], 0, 0, 0);
            }
        }
    }

    // finale: reduce l over quads (lanes l15, l15+16, l15+32, l15+48)
    float l = l_part + __shfl_xor(l_part, 16);
    l += __shfl_xor(l, 32);
    // O rows are qrow = quad*4+r; l for that qrow sits at lane quad*4+r
    float inv[4];
#pragma unroll
    for (int r = 0; r < 4; ++r) inv[r] = 1.0f / __shfl(l, quad * 4 + r);

    const int b = bh / NH, h = bh % NH;
#pragma unroll
    for (int r = 0; r < 4; ++r) {
        size_t row = (size_t)b * NSEQ + qt * 64 + wid * 16 + quad * 4 + r;
#pragma unroll
        for (int t = 0; t < 4; ++t)
            AO[row * CDIM + h * HD + t * 16 + l15] = f2bf(O[t][r] * inv[r]);
    }
}

// ---------------------------------------------------------------------------
// Kernel 3: out = AO @ Wproj^T + bias, bf16 MFMA. Tiles 128x128x64,
// 4 waves (2x2), each wave 64x64 via 4x4 MFMA 16x16x32 tiles.
// ---------------------------------------------------------------------------
__global__ __launch_bounds__(256)
void proj_kernel(const u16* __restrict__ A, const u16* __restrict__ Wp,
                 const float* __restrict__ bias, float* __restrict__ out)
{
    __shared__ __align__(16) u16 As[128 * LSTR];
    __shared__ __align__(16) u16 Bs[128 * LSTR];
    const int tid  = threadIdx.x;
    const int lane = tid & 63;
    const int wid  = tid >> 6;
    const int l15  = lane & 15;
    const int quad = lane >> 4;
    const int wr = wid >> 1, wc = wid & 1;
    const int m0 = blockIdx.x * 128;
    const int n0 = blockIdx.y * 128;

    f32x4 acc[4][4];
#pragma unroll
    for (int mi = 0; mi < 4; ++mi)
#pragma unroll
        for (int ni = 0; ni < 4; ++ni)
            acc[mi][ni] = (f32x4){0.f, 0.f, 0.f, 0.f};

    for (int kt = 0; kt < CDIM; kt += 64) {
        __syncthreads();
#pragma unroll
        for (int it = 0; it < 4; ++it) {
            int idx = tid + 256 * it;
            int row = idx >> 3, c8 = (idx & 7) << 3;
            *(uint4*)&As[row * LSTR + c8] =
                *(const uint4*)&A[(size_t)(m0 + row) * CDIM + kt + c8];
            *(uint4*)&Bs[row * LSTR + c8] =
                *(const uint4*)&Wp[(size_t)(n0 + row) * CDIM + kt + c8];
        }
        __syncthreads();
#pragma unroll
        for (int k = 0; k < 2; ++k) {
            bf16x8 af[4], bf[4];
#pragma unroll
            for (int mi = 0; mi < 4; ++mi)
                af[mi] = *(const bf16x8*)
                    &As[(wr * 64 + mi * 16 + l15) * LSTR + quad * 8 + 32 * k];
#pragma unroll
            for (int ni = 0; ni < 4; ++ni)
                bf[ni] = *(const bf16x8*)
                    &Bs[(wc * 64 + ni * 16 + l15) * LSTR + quad * 8 + 32 * k];
#pragma unroll
            for (int mi = 0; mi < 4; ++mi)
#pragma unroll
                for (int ni = 0; ni < 4; ++ni)
                    acc[mi][ni] = __builtin_amdgcn_mfma_f32_16x16x32_bf16(
                        af[mi], bf[ni], acc[mi][ni], 0, 0, 0);
        }
    }

#pragma unroll
    for (int ni = 0; ni < 4; ++ni) {
        int col = n0 + wc * 64 + ni * 16 + l15;
        float bb = bias[col];
#pragma unroll
        for (int mi = 0; mi < 4; ++mi) {
            int row = m0 + wr * 64 + mi * 16 + quad * 4;
#pragma unroll
            for (int r = 0; r < 4; ++r)
                out[(size_t)(row + r) * CDIM + col] = acc[mi][ni][r] + bb;
        }
    }
}

// ---------------------------------------------------------------------------
extern "C" void kernel_launch(void* const* d_in, const int* in_sizes, int n_in,
                              void* d_out, int out_size, void* d_ws,
                              size_t ws_size, hipStream_t stream)
{
    const float* X     = (const float*)d_in[0];   // [2, 2048, 768]
    const float* Wqkv  = (const float*)d_in[1];   // [2304, 768]
    const float* Wproj = (const float*)d_in[2];   // [768, 768]
    const float* bias  = (const float*)d_in[3];   // [768]
    float* out = (float*)d_out;                   // [2, 2048, 768]

    const size_t per_buf = (size_t)NB * NH * NSEQ * HD;   // 3145728
    const size_t xw_sz   = per_buf;                       // 4096*768
    const size_t wq_sz   = (size_t)3 * CDIM * CDIM;       // 2304*768
    u16* Qb  = (u16*)d_ws;
    u16* Kb  = Qb + per_buf;
    u16* Vb  = Kb + per_buf;                      // [B,H,64,N]
    u16* AOb = Vb + per_buf;                      // [4096, 768] bf16
    u16* Wpb = AOb + per_buf;                     // [768, 768] bf16
    u16* Xhi = Wpb + (size_t)CDIM * CDIM;
    u16* Xlo = Xhi + xw_sz;
    u16* Whi = Xlo + xw_sz;
    u16* Wlo = Whi + wq_sz;

    split_kernel<<<dim3(xw_sz / 1024), 256, 0, stream>>>(X, Xhi, Xlo);
    split_kernel<<<dim3(wq_sz / 1024), 256, 0, stream>>>(Wqkv, Whi, Wlo);
    wconv_kernel<<<dim3(CDIM * CDIM / 1024), 256, 0, stream>>>(Wproj, Wpb);
    qkv_mfma_kernel<<<dim3(32, 18), 256, 0, stream>>>(Xhi, Xlo, Whi, Wlo,
                                                      Qb, Kb, Vb);
    attn_kernel<<<dim3(32, 24), 256, 0, stream>>>(Qb, Kb, Vb, AOb);
    proj_kernel<<<dim3(32, 6), 256, 0, stream>>>(AOb, Wpb, bias, out);
}